// Round 11
// baseline (102.779 us; speedup 1.0000x reference)
//
#include <hip/hip_runtime.h>

#define B_SZ   1024
#define OUT_SZ 512
#define IN_SZ  1024

#define MB 64                 // b-rows per block
#define NB 64                 // o-rows per block
#define KSPLIT 4
#define KSL (IN_SZ / KSPLIT)  // 256 raw k per block
#define CH  64                // raw k per chunk
#define NCH (KSL / CH)        // 4 chunks
#define MAGIC 0x5F3759DFu

typedef __bf16 bf16x8 __attribute__((ext_vector_type(8)));
typedef __bf16 bf16x4 __attribute__((ext_vector_type(4)));
typedef float  f32x4  __attribute__((ext_vector_type(4)));

// LDS fragment-native bf16 tiles: [seg][s][frag16][slot][j]
//   seg A: 0=x^2, 1=x   seg B: 0=u^2, 1=-2u^2w   ((uw)^2 via fp32 VALU)
#define A_IDX(seg, s, mf, slot) (((((seg)*2 + (s))*4 + (mf))*64 + (slot))*8)
#define B_IDX(seg, s, nf, slot) (((((seg)*2 + (s))*4 + (nf))*64 + (slot))*8)

// ws layout: part[4][128][4096] f32 = 8 MB | flags[128*4] u32
// SINGLE dispatch: split-K=4 with in-kernel fixup. kz>0 blocks publish their
// partial tile with a release flag; the kz==0 block spin-acquires the 3 flags,
// sums, and writes the exp/mix epilogue directly to d_out. Each extra dispatch
// costs ~8us of graph-replay overhead (R4/R6/R9/R10 regression fit), so one
// dispatch beats the cleaner two-kernel split.
__global__ __launch_bounds__(256) void rbf_one(
    const float* __restrict__ x, const float* __restrict__ w,
    const float* __restrict__ u, const float* __restrict__ andor,
    float* __restrict__ part, unsigned int* __restrict__ flags,
    float* __restrict__ out)
{
    __shared__ __bf16 Asm[2 * 2 * 4 * 64 * 8];   // 16 KB
    __shared__ __bf16 Bsm[2 * 2 * 4 * 64 * 8];   // 16 KB
    __shared__ float  Rsm[64];

    const int t     = threadIdx.x;
    const int lane  = t & 63;
    const int wv    = t >> 6;
    const int wm    = wv >> 1;
    const int wn    = wv & 1;
    const int bid   = blockIdx.x;
    // XCD swizzle: bid&7 == XCD -> o-slice's u/w stays hot in that XCD's L2
    const int yt    = bid & 7;                   // o-tile (8)
    const int xt    = (bid >> 3) & 15;           // b-tile (16)
    const int kz    = bid >> 7;                  // k-slice (4)
    const int tile  = xt * 8 + yt;               // 0..127
    const int mBase = xt * MB;
    const int nBase = yt * NB;
    const int kBase = kz * KSL;

    f32x4 acc[2][2] = {};
    float r_acc[4] = {0.f, 0.f, 0.f, 0.f};

    float4 xr[4], ur[4], wr[4];

    auto load_regs = [&](int c) {
        #pragma unroll
        for (int i = 0; i < 4; ++i) {
            int id  = i * 256 + t;
            int row = id >> 4;
            int gk  = kBase + c * CH + (id & 15) * 4;
            xr[i] = *(const float4*)&x[(size_t)(mBase + row) * IN_SZ + gk];
            ur[i] = *(const float4*)&u[(size_t)(nBase + row) * IN_SZ + gk];
            wr[i] = *(const float4*)&w[(size_t)(nBase + row) * IN_SZ + gk];
        }
    };

    auto write_lds = [&]() {
        #pragma unroll
        for (int i = 0; i < 4; ++i) {
            int id    = i * 256 + t;
            int row   = id >> 4;
            int row16 = row & 15;
            int frag  = row >> 4;
            int kl    = (id & 15) * 4;
            int s     = kl >> 5;
            int quad  = (kl >> 3) & 3;
            int j0    = kl & 7;
            int slot  = quad * 16 + ((row16 ^ quad) & 15);

            float xv[4]  = {xr[i].x, xr[i].y, xr[i].z, xr[i].w};
            float uv[4]  = {ur[i].x, ur[i].y, ur[i].z, ur[i].w};
            float wv4[4] = {wr[i].x, wr[i].y, wr[i].z, wr[i].w};
            bf16x4 a0, a1, b0, b1;
            #pragma unroll
            for (int e = 0; e < 4; ++e) {
                float xe = xv[e], ue = uv[e], we = wv4[e];
                float u2 = ue * ue;
                float uw = ue * we;
                a0[e] = (__bf16)(xe * xe);
                a1[e] = (__bf16)xe;
                b0[e] = (__bf16)u2;
                b1[e] = (__bf16)(-2.f * u2 * we);
                r_acc[i] = fmaf(uw, uw, r_acc[i]);   // exact fp32 bias term
            }
            *(bf16x4*)&Asm[A_IDX(0, s, frag, slot) + j0] = a0;
            *(bf16x4*)&Asm[A_IDX(1, s, frag, slot) + j0] = a1;
            *(bf16x4*)&Bsm[B_IDX(0, s, frag, slot) + j0] = b0;
            *(bf16x4*)&Bsm[B_IDX(1, s, frag, slot) + j0] = b1;
        }
    };

    const int r_quad = lane >> 4;
    const int r_slot = r_quad * 16 + (((lane & 15) ^ r_quad) & 15);
    const int mf0 = wm * 2, nf0 = wn * 2;

    load_regs(0);

    for (int c = 0; c < NCH; ++c) {
        __syncthreads();
        write_lds();
        __syncthreads();
        if (c + 1 < NCH) load_regs(c + 1);

        #pragma unroll
        for (int seg = 0; seg < 2; ++seg)
            #pragma unroll
            for (int s = 0; s < 2; ++s) {
                bf16x8 am0 = *(const bf16x8*)&Asm[A_IDX(seg, s, mf0,     r_slot)];
                bf16x8 am1 = *(const bf16x8*)&Asm[A_IDX(seg, s, mf0 + 1, r_slot)];
                bf16x8 bn0 = *(const bf16x8*)&Bsm[B_IDX(seg, s, nf0,     r_slot)];
                bf16x8 bn1 = *(const bf16x8*)&Bsm[B_IDX(seg, s, nf0 + 1, r_slot)];
                acc[0][0] = __builtin_amdgcn_mfma_f32_16x16x32_bf16(am0, bn0, acc[0][0], 0, 0, 0);
                acc[0][1] = __builtin_amdgcn_mfma_f32_16x16x32_bf16(am0, bn1, acc[0][1], 0, 0, 0);
                acc[1][0] = __builtin_amdgcn_mfma_f32_16x16x32_bf16(am1, bn0, acc[1][0], 0, 0, 0);
                acc[1][1] = __builtin_amdgcn_mfma_f32_16x16x32_bf16(am1, bn1, acc[1][1], 0, 0, 0);
            }
    }

    // reduce r_acc over the 16 staging threads sharing each o-row
    #pragma unroll
    for (int d = 1; d < 16; d <<= 1) {
        #pragma unroll
        for (int i = 0; i < 4; ++i) r_acc[i] += __shfl_xor(r_acc[i], d);
    }
    __syncthreads();
    if ((t & 15) == 0) {
        #pragma unroll
        for (int i = 0; i < 4; ++i) Rsm[i * 16 + (t >> 4)] = r_acc[i];
    }
    __syncthreads();

    // partial tile (tile-local 64x64): C/D col = lane&15 (o), row = quad*4+reg
    float* pt = &part[((size_t)kz * 128 + tile) * 4096];
    const int col = lane & 15;
    #pragma unroll
    for (int mi = 0; mi < 2; ++mi) {
        int row0 = (wm * 2 + mi) * 16 + r_quad * 4;
        #pragma unroll
        for (int ni = 0; ni < 2; ++ni) {
            int oloc = (wn * 2 + ni) * 16 + col;
            float rr = Rsm[oloc];
            #pragma unroll
            for (int r = 0; r < 4; ++r)
                pt[(row0 + r) * 64 + oloc] = acc[mi][ni][r] + rr;
        }
    }

    __syncthreads();                          // all partial stores issued
    if (kz != 0) {
        if (t == 0) {
            __threadfence();                  // release this block's stores
            __hip_atomic_store(&flags[tile * 4 + kz], MAGIC,
                               __ATOMIC_RELEASE, __HIP_MEMORY_SCOPE_AGENT);
        }
        return;
    }

    // kz==0: acquire siblings, then finalize the tile into d_out
    if (t < KSPLIT - 1) {
        while (__hip_atomic_load(&flags[tile * 4 + 1 + t],
                                 __ATOMIC_ACQUIRE, __HIP_MEMORY_SCOPE_AGENT) != MAGIC)
            __builtin_amdgcn_s_sleep(1);
    }
    __syncthreads();
    __threadfence();

    const float* p0 = &part[(size_t)tile * 4096];
    #pragma unroll
    for (int i = 0; i < 4; ++i) {
        int f4 = t + i * 256;                 // float4 index in tile, 0..1023
        float4 z = *(const float4*)&p0[f4 * 4];
        #pragma unroll
        for (int k = 1; k < KSPLIT; ++k) {
            const float4 p = *(const float4*)&p0[(size_t)k * 128 * 4096 + f4 * 4];
            z.x += p.x; z.y += p.y; z.z += p.z; z.w += p.w;
        }
        int row_l = f4 >> 4;
        int col_l = (f4 & 15) * 4;
        int o = nBase + col_l;
        const float4 a = *(const float4*)&andor[o];
        float4 ov;
        ov.x = fmaf(__expf(-z.x), 1.f - 2.f * a.x, a.x);
        ov.y = fmaf(__expf(-z.y), 1.f - 2.f * a.y, a.y);
        ov.z = fmaf(__expf(-z.z), 1.f - 2.f * a.z, a.z);
        ov.w = fmaf(__expf(-z.w), 1.f - 2.f * a.w, a.w);
        *(float4*)&out[(size_t)(mBase + row_l) * OUT_SZ + o] = ov;
    }
}

extern "C" void kernel_launch(void* const* d_in, const int* in_sizes, int n_in,
                              void* d_out, int out_size, void* d_ws, size_t ws_size,
                              hipStream_t stream) {
    const float* x = (const float*)d_in[0];   // [B, IN]
    const float* w = (const float*)d_in[1];   // [OUT, IN]
    const float* u = (const float*)d_in[2];   // [OUT, IN]
    const float* a = (const float*)d_in[3];   // [1, OUT]
    float* out = (float*)d_out;               // [B, OUT]

    float* part = (float*)d_ws;                               // 8 MB
    unsigned int* flags = (unsigned int*)((char*)d_ws + (size_t)8 * 1024 * 1024);

    rbf_one<<<dim3(16 * 8 * KSPLIT), dim3(256), 0, stream>>>(x, w, u, a, part, flags, out);
}